// Round 1
// baseline (7996.776 us; speedup 1.0000x reference)
//
#include <hip/hip_runtime.h>

#define B_SZ 512
#define T_ENC 140
#define E_DIM 256
#define H_DIM 512
#define O_DIM 64
#define PRED 140
#define T_TOT 280
#define NBLK 256

typedef short bf16x8 __attribute__((ext_vector_type(8)));
typedef float f32x4 __attribute__((ext_vector_type(4)));

static __device__ __forceinline__ unsigned short f2b(float x){
  union { float f; unsigned u; } v; v.f = x;
  unsigned r = v.u + 0x7fffu + ((v.u >> 16) & 1u);
  return (unsigned short)(r >> 16);
}
static __device__ __forceinline__ float sigmoidf_(float x){
  return 1.0f / (1.0f + __expf(-x));
}
static __device__ __forceinline__ float tanhf_(float x){
  float e2 = __expf(-2.0f * fabsf(x));
  float t = (1.0f - e2) / (1.0f + e2);
  return x < 0.0f ? -t : t;
}

__global__ void k_cast(const float* __restrict__ src, unsigned short* __restrict__ dst, int n){
  int i = blockIdx.x * 256 + threadIdx.x;
  if (i < n) dst[i] = f2b(src[i]);
}

// out_W (E x H) -> outWT16 (H x E) bf16
__global__ void k_transpose_cast(const float* __restrict__ src, unsigned short* __restrict__ dst){
  int i = blockIdx.x * 256 + threadIdx.x;   // over H*E = 131072
  int j = i >> 8;        // 0..511 row of dst
  int k = i & 255;       // 0..255
  dst[i] = f2b(src[k * H_DIM + j]);
}

__global__ void k_init_h(const float* __restrict__ eh, float* __restrict__ h, unsigned short* __restrict__ h16){
  int i = blockIdx.x * 256 + threadIdx.x;   // B*H
  float v = eh[i];
  h[i] = v; h16[i] = f2b(v);
}

__global__ void k_x0(const float* __restrict__ enc, unsigned short* __restrict__ x016){
  int i = blockIdx.x * 256 + threadIdx.x;   // B*E
  int b = i >> 8; int k = i & 255;
  x016[i] = f2b(enc[((size_t)b * T_ENC + (T_ENC - 1)) * E_DIM + k]);
}

// bias_big = [emb_b + emb_W@out_b (512) | b_hh (1536) | reg_b + reg_W@out_b (64)]
__global__ void k_bias(const float* __restrict__ embW, const float* __restrict__ emb_b,
                       const float* __restrict__ out_b, const float* __restrict__ b_hh,
                       const float* __restrict__ regW, const float* __restrict__ reg_b,
                       float* __restrict__ bias_big){
  int i = blockIdx.x * 256 + threadIdx.x;
  if (i < 512){
    float s = emb_b[i];
    for (int k = 0; k < 256; k++) s += embW[i * 256 + k] * out_b[k];
    bias_big[i] = s;
  } else if (i < 2048){
    bias_big[i] = b_hh[i - 512];
  } else if (i < 2112){
    int o = i - 2048;
    float s = reg_b[o];
    for (int k = 0; k < 256; k++) s += regW[o * 256 + k] * out_b[k];
    bias_big[i] = s;
  }
}

// Generic C = A @ W^T (+bias). A: M x K (bf16 or f32), W: N x K bf16 row-major.
// mode 0: f32 out (ldc); 1: bf16 out; 2: relu + bf16 out; 3: f32 out with encoder (b,t) row remap
__global__ __launch_bounds__(256)
void k_gemm(const void* __restrict__ Aptr, int a_is_f32,
            const unsigned short* __restrict__ W,
            const float* __restrict__ bias,
            void* __restrict__ Cptr, int mode,
            int M, int N, int K, int ldc)
{
  const int lane = threadIdx.x & 63;
  const int wave = threadIdx.x >> 6;
  const int ln = lane & 15;
  const int kq = lane >> 4;
  const int m0 = blockIdx.y * 64 + wave * 16;
  const int n0 = blockIdx.x * 64;

  f32x4 acc[4] = {};
  const int arow = m0 + ln;
  const unsigned short* wp = W + (size_t)(n0 + ln) * K + kq * 8;
  const int nk = K >> 5;

  if (a_is_f32){
    const float* ap = (const float*)Aptr + (size_t)arow * K + kq * 8;
    for (int t = 0; t < nk; ++t){
      f32x4 u0 = *(const f32x4*)(ap);
      f32x4 u1 = *(const f32x4*)(ap + 4);
      bf16x8 af;
      af[0] = (short)f2b(u0[0]); af[1] = (short)f2b(u0[1]);
      af[2] = (short)f2b(u0[2]); af[3] = (short)f2b(u0[3]);
      af[4] = (short)f2b(u1[0]); af[5] = (short)f2b(u1[1]);
      af[6] = (short)f2b(u1[2]); af[7] = (short)f2b(u1[3]);
      #pragma unroll
      for (int j = 0; j < 4; j++){
        bf16x8 wf = *(const bf16x8*)(wp + (size_t)(16 * j) * K);
        acc[j] = __builtin_amdgcn_mfma_f32_16x16x32_bf16(af, wf, acc[j], 0, 0, 0);
      }
      ap += 32; wp += 32;
    }
  } else {
    const unsigned short* ap = (const unsigned short*)Aptr + (size_t)arow * K + kq * 8;
    for (int t = 0; t < nk; ++t){
      bf16x8 af = *(const bf16x8*)ap;
      #pragma unroll
      for (int j = 0; j < 4; j++){
        bf16x8 wf = *(const bf16x8*)(wp + (size_t)(16 * j) * K);
        acc[j] = __builtin_amdgcn_mfma_f32_16x16x32_bf16(af, wf, acc[j], 0, 0, 0);
      }
      ap += 32; wp += 32;
    }
  }

  #pragma unroll
  for (int j = 0; j < 4; j++){
    int col = n0 + 16 * j + ln;
    float bv = bias ? bias[col] : 0.0f;
    #pragma unroll
    for (int r = 0; r < 4; r++){
      int orow = m0 + kq * 4 + r;
      float v = acc[j][r] + bv;
      if (mode == 0){
        ((float*)Cptr)[(size_t)orow * ldc + col] = v;
      } else if (mode == 1){
        ((unsigned short*)Cptr)[(size_t)orow * ldc + col] = f2b(v);
      } else if (mode == 2){
        ((unsigned short*)Cptr)[(size_t)orow * ldc + col] = f2b(v > 0.f ? v : 0.f);
      } else {
        int bb = orow / T_ENC;
        int tt = orow - bb * T_ENC;
        ((float*)Cptr)[((size_t)bb * T_TOT + tt) * O_DIM + col] = v;
      }
    }
  }
}

// ---------------- persistent GRU loop ----------------

// grid barrier: cumulative counter, release-add / relaxed-poll / acquire-fence.
static __device__ __forceinline__ void gbar(unsigned* cnt, unsigned tgt){
  __syncthreads();
  if (threadIdx.x == 0){
    __builtin_amdgcn_fence(__ATOMIC_RELEASE, "agent");
    __hip_atomic_fetch_add(cnt, 1u, __ATOMIC_RELAXED, __HIP_MEMORY_SCOPE_AGENT);
    while (__hip_atomic_load(cnt, __ATOMIC_RELAXED, __HIP_MEMORY_SCOPE_AGENT) < tgt){
      __builtin_amdgcn_s_sleep(2);
    }
    __builtin_amdgcn_fence(__ATOMIC_ACQUIRE, "agent");
  }
  __syncthreads();
}

// Phase A per-wave GEMM: NMF m-frags x 1 n-frag, K=512, W from LDS (k-major granules).
template<int NMF>
static __device__ __forceinline__ void phaseA(
    const short* wA,
    const unsigned short* __restrict__ h16,
    unsigned short* __restrict__ e16,
    float* __restrict__ gh,
    float* __restrict__ out,
    int mbase, int ln, int kq, int colA, float bvA, int s)
{
  f32x4 acc[NMF];
  #pragma unroll
  for (int f = 0; f < NMF; ++f) acc[f] = (f32x4){0.f, 0.f, 0.f, 0.f};
  #pragma unroll
  for (int t = 0; t < 16; ++t){
    bf16x8 wf = *(const bf16x8*)(wA + (t * 64 + ln * 4 + kq) * 8);
    #pragma unroll
    for (int f = 0; f < NMF; ++f){
      bf16x8 af = *(const bf16x8*)(h16 + (size_t)(mbase + f * 16 + ln) * H_DIM + t * 32 + kq * 8);
      acc[f] = __builtin_amdgcn_mfma_f32_16x16x32_bf16(af, wf, acc[f], 0, 0, 0);
    }
  }
  #pragma unroll
  for (int f = 0; f < NMF; ++f){
    #pragma unroll
    for (int r = 0; r < 4; ++r){
      int b = mbase + f * 16 + kq * 4 + r;
      float v = acc[f][r] + bvA;
      if (colA < 512){
        e16[(size_t)b * H_DIM + colA] = f2b(v > 0.f ? v : 0.f);
      } else if (colA < 2048){
        gh[(size_t)b * 1536 + (colA - 512)] = v;
      } else {
        out[((size_t)b * T_TOT + T_ENC + s) * O_DIM + (colA - 2048)] = v;
      }
    }
  }
}

// One block per CU. LDS: A-slice 16KB (16 cols of Wbig) + B-slice 48KB (48 cols of w_ih).
// A: 132 col-tiles of 16; tiles 0..123 m-split over 2 blocks, 124..131 full-M on blocks 248..255.
// B: 32 j-tiles x 8 m-slices (64 rows), waves 0..3 active (1 m-frag x 3 gates), gating in-lane.
__global__ __launch_bounds__(512, 2)
void k_persist(const unsigned short* __restrict__ Wbig,
               const unsigned short* __restrict__ wih16,
               const float* __restrict__ bias_big,
               const float* __restrict__ b_ih,
               unsigned short* __restrict__ e16,
               float* __restrict__ gh,
               float* __restrict__ h,
               unsigned short* __restrict__ h16,
               float* __restrict__ out,
               unsigned* __restrict__ barcnt)
{
  __shared__ short lds_s[32768];          // 64 KiB exactly: [0,8192) A, [8192,32768) B (shorts)
  short* wA = lds_s;
  short* wB = lds_s + 8192;

  const int g    = blockIdx.x;
  const int tid  = threadIdx.x;
  const int wv   = tid >> 6;
  const int lane = tid & 63;
  const int ln   = lane & 15;
  const int kq   = lane >> 4;

  const int at  = (g < 248) ? (g >> 1) : (124 + (g - 248));
  const int jt  = g & 31;
  const int mtB = g >> 5;

  // ---- stage weights into LDS (once), k-major 16B granules ----
  // A: granule (kk,c) -> phys (kk>>2)*64 + c*4 + (kk&3); wave-read for (t) is contiguous 1KB
  for (int q = tid; q < 1024; q += 512){
    int kk = q & 63, c = q >> 6;
    bf16x8 v = *(const bf16x8*)(Wbig + (size_t)(at * 16 + c) * H_DIM + kk * 8);
    int p = ((kk >> 2) << 6) + (c << 2) + (kk & 3);
    *(bf16x8*)(wA + p * 8) = v;
  }
  // B: 48 cols = gate*16 + ln; granule (kk,c) -> phys (kk>>2)*192 + c*4 + (kk&3)
  for (int q = tid; q < 3072; q += 512){
    int kk = q & 63, c = q >> 6;
    int row = ((c >> 4) << 9) + jt * 16 + (c & 15);
    bf16x8 v = *(const bf16x8*)(wih16 + (size_t)row * H_DIM + kk * 8);
    int p = (kk >> 2) * 192 + (c << 2) + (kk & 3);
    *(bf16x8*)(wB + p * 8) = v;
  }
  __syncthreads();

  // hoisted per-thread constants
  const int jcol = jt * 16 + ln;
  const float bR = b_ih[jcol], bZ = b_ih[512 + jcol], bN = b_ih[1024 + jcol];
  const int colA = at * 16 + ln;
  const float bvA = bias_big[colA];

  unsigned gen = 0;
  for (int s = 0; s < PRED; ++s){
    // ---- phase B: gi = e16 @ w_ih^T slice, GRU gating -> h, h16 ----
    if (wv < 4){
      const int m0 = mtB * 64 + wv * 16;
      f32x4 aR = {}, aZ = {}, aN = {};
      const unsigned short* ap = e16 + (size_t)(m0 + ln) * H_DIM + kq * 8;
      const short* lb = wB + (ln * 4 + kq) * 8;
      #pragma unroll
      for (int t = 0; t < 16; ++t){
        bf16x8 af = *(const bf16x8*)ap;
        aR = __builtin_amdgcn_mfma_f32_16x16x32_bf16(af, *(const bf16x8*)(lb + (t * 192      ) * 8), aR, 0, 0, 0);
        aZ = __builtin_amdgcn_mfma_f32_16x16x32_bf16(af, *(const bf16x8*)(lb + (t * 192 +  64) * 8), aZ, 0, 0, 0);
        aN = __builtin_amdgcn_mfma_f32_16x16x32_bf16(af, *(const bf16x8*)(lb + (t * 192 + 128) * 8), aN, 0, 0, 0);
        ap += 32;
      }
      #pragma unroll
      for (int r = 0; r < 4; ++r){
        int b = m0 + kq * 4 + r;
        const float* ghrow = gh + (size_t)b * 1536;
        float rg = sigmoidf_(aR[r] + bR + ghrow[jcol]);
        float z  = sigmoidf_(aZ[r] + bZ + ghrow[512 + jcol]);
        float nn = tanhf_(aN[r] + bN + rg * ghrow[1024 + jcol]);
        float hv = (1.f - z) * nn + z * h[(size_t)b * H_DIM + jcol];
        h[(size_t)b * H_DIM + jcol] = hv;
        h16[(size_t)b * H_DIM + jcol] = f2b(hv);
      }
    }
    gen++; gbar(barcnt, gen * NBLK);

    // ---- phase A: T = h16 @ Wbig^T slice -> e16 / gh / out ----
    if (s < PRED - 1 || at >= 128){
      if (g < 248){
        phaseA<2>(wA, h16, e16, gh, out, (g & 1) * 256 + wv * 32, ln, kq, colA, bvA, s);
      } else {
        phaseA<4>(wA, h16, e16, gh, out, wv * 64, ln, kq, colA, bvA, s);
      }
    }
    if (s < PRED - 1){
      gen++; gbar(barcnt, gen * NBLK);
    }
  }
}

extern "C" void kernel_launch(void* const* d_in, const int* in_sizes, int n_in,
                              void* d_out, int out_size, void* d_ws, size_t ws_size,
                              hipStream_t stream)
{
  const float* enc   = (const float*)d_in[0];
  const float* ehid  = (const float*)d_in[1];
  const float* embW  = (const float*)d_in[2];
  const float* emb_b = (const float*)d_in[3];
  const float* w_ih  = (const float*)d_in[4];
  const float* w_hh  = (const float*)d_in[5];
  const float* b_ih  = (const float*)d_in[6];
  const float* b_hh  = (const float*)d_in[7];
  const float* out_W = (const float*)d_in[8];
  const float* out_b = (const float*)d_in[9];
  const float* reg_W = (const float*)d_in[10];
  const float* reg_b = (const float*)d_in[11];
  float* out = (float*)d_out;

  char* ws = (char*)d_ws;
  size_t off = 0;
  auto alloc = [&](size_t bytes)->char*{
    char* p = ws + off; off += (bytes + 255) & ~(size_t)255; return p;
  };
  unsigned short* Wbig    = (unsigned short*)alloc((size_t)2112 * 512 * 2);
  unsigned short* wih16   = (unsigned short*)alloc((size_t)1536 * 512 * 2);
  unsigned short* embW16  = (unsigned short*)alloc((size_t)512 * 256 * 2);
  unsigned short* regW16  = (unsigned short*)alloc((size_t)64 * 256 * 2);
  unsigned short* outWT16 = (unsigned short*)alloc((size_t)512 * 256 * 2);
  float*          bias_big= (float*)alloc((size_t)2112 * 4);
  unsigned short* e16     = (unsigned short*)alloc((size_t)512 * 512 * 2);
  float*          gh      = (float*)alloc((size_t)512 * 1536 * 4);
  float*          h       = (float*)alloc((size_t)512 * 512 * 4);
  unsigned short* h16     = (unsigned short*)alloc((size_t)512 * 512 * 2);
  unsigned short* x016    = (unsigned short*)alloc((size_t)512 * 256 * 2);
  unsigned*       barcnt  = (unsigned*)alloc(256);

  hipMemsetAsync(barcnt, 0, 64, stream);

  // ---- precompute (runs every call; ws is re-poisoned) ----
  k_cast<<<(1536 * 512) / 256, 256, 0, stream>>>(w_ih, wih16, 1536 * 512);
  k_cast<<<(1536 * 512) / 256, 256, 0, stream>>>(w_hh, Wbig + (size_t)512 * 512, 1536 * 512);
  k_cast<<<(512 * 256) / 256, 256, 0, stream>>>(embW, embW16, 512 * 256);
  k_cast<<<(64 * 256) / 256, 256, 0, stream>>>(reg_W, regW16, 64 * 256);
  k_transpose_cast<<<512, 256, 0, stream>>>(out_W, outWT16);
  k_bias<<<9, 256, 0, stream>>>(embW, emb_b, out_b, b_hh, reg_W, reg_b, bias_big);
  k_init_h<<<(512 * 512) / 256, 256, 0, stream>>>(ehid, h, h16);
  k_x0<<<(512 * 256) / 256, 256, 0, stream>>>(enc, x016);

  // W_comb = emb_W @ out_W  -> Wbig rows [0,512)
  k_gemm<<<dim3(8, 8), 256, 0, stream>>>(embW, 1, outWT16, nullptr, Wbig, 1, 512, 512, 256, 512);
  // W_or = reg_W @ out_W  -> Wbig rows [2048,2112)
  k_gemm<<<dim3(8, 1), 256, 0, stream>>>(reg_W, 1, outWT16, nullptr, Wbig + (size_t)2048 * 512, 1, 64, 512, 256, 512);
  // e0 = relu(x0 @ emb_W^T + emb_b)
  k_gemm<<<dim3(8, 8), 256, 0, stream>>>(x016, 0, embW16, emb_b, e16, 2, 512, 512, 256, 512);
  // gh0 = h0 @ w_hh^T + b_hh
  k_gemm<<<dim3(24, 8), 256, 0, stream>>>(h16, 0, Wbig + (size_t)512 * 512, b_hh, gh, 0, 512, 1536, 512, 1536);
  // encoder projection: out[:, 0:140, :] = enc @ reg_W^T + reg_b
  k_gemm<<<dim3(1, 1120), 256, 0, stream>>>(enc, 1, regW16, reg_b, out, 3, 71680, 64, 256, 0);

  // ---- 140 GRU steps in ONE persistent kernel (2 grid barriers/step) ----
  k_persist<<<dim3(NBLK), dim3(512), 0, stream>>>(Wbig, wih16, bias_big, b_ih,
                                                  e16, gh, h, h16, out, barcnt);
}

// Round 2
// 5468.789 us; speedup vs baseline: 1.4623x; 1.4623x over previous
//
#include <hip/hip_runtime.h>

#define B_SZ 512
#define T_ENC 140
#define E_DIM 256
#define H_DIM 512
#define O_DIM 64
#define PRED 140
#define T_TOT 280
#define NBLK 256

typedef short bf16x8 __attribute__((ext_vector_type(8)));
typedef float f32x4 __attribute__((ext_vector_type(4)));

static __device__ __forceinline__ unsigned short f2b(float x){
  union { float f; unsigned u; } v; v.f = x;
  unsigned r = v.u + 0x7fffu + ((v.u >> 16) & 1u);
  return (unsigned short)(r >> 16);
}
static __device__ __forceinline__ float sigmoidf_(float x){
  return 1.0f / (1.0f + __expf(-x));
}
static __device__ __forceinline__ float tanhf_(float x){
  float e2 = __expf(-2.0f * fabsf(x));
  float t = (1.0f - e2) / (1.0f + e2);
  return x < 0.0f ? -t : t;
}

// ---- device-coherent (L3) access: bypass L1/L2 so no fence/invalidate is ever needed ----
static __device__ __forceinline__ void st_wt_u16(unsigned short* p, unsigned v){
  asm volatile("global_store_short %0, %1, off sc0 sc1" :: "v"(p), "v"(v) : "memory");
}
static __device__ __forceinline__ void st_wt_f32(float* p, float v){
  asm volatile("global_store_dword %0, %1, off sc0 sc1" :: "v"(p), "v"(v) : "memory");
}
static __device__ __forceinline__ bf16x8 ld_bp(const unsigned short* p){
  f32x4 r;
  asm volatile("global_load_dwordx4 %0, %1, off sc0 sc1" : "=v"(r) : "v"(p));
  union { f32x4 f; bf16x8 b; } u; u.f = r; return u.b;
}
static __device__ __forceinline__ float ld_bp_f32(const float* p){
  float r;
  asm volatile("global_load_dword %0, %1, off sc0 sc1" : "=v"(r) : "v"(p));
  return r;
}
static __device__ __forceinline__ void wait_vm0(){
  asm volatile("s_waitcnt vmcnt(0)" ::: "memory");
  __builtin_amdgcn_sched_barrier(0);
}

__global__ void k_cast(const float* __restrict__ src, unsigned short* __restrict__ dst, int n){
  int i = blockIdx.x * 256 + threadIdx.x;
  if (i < n) dst[i] = f2b(src[i]);
}

// out_W (E x H) -> outWT16 (H x E) bf16
__global__ void k_transpose_cast(const float* __restrict__ src, unsigned short* __restrict__ dst){
  int i = blockIdx.x * 256 + threadIdx.x;   // over H*E = 131072
  int j = i >> 8;
  int k = i & 255;
  dst[i] = f2b(src[k * H_DIM + j]);
}

__global__ void k_init_h(const float* __restrict__ eh, float* __restrict__ h, unsigned short* __restrict__ h16){
  int i = blockIdx.x * 256 + threadIdx.x;   // B*H
  float v = eh[i];
  h[i] = v; h16[i] = f2b(v);
}

__global__ void k_x0(const float* __restrict__ enc, unsigned short* __restrict__ x016){
  int i = blockIdx.x * 256 + threadIdx.x;   // B*E
  int b = i >> 8; int k = i & 255;
  x016[i] = f2b(enc[((size_t)b * T_ENC + (T_ENC - 1)) * E_DIM + k]);
}

// bias_big = [emb_b + emb_W@out_b (512) | b_hh (1536) | reg_b + reg_W@out_b (64)]
__global__ void k_bias(const float* __restrict__ embW, const float* __restrict__ emb_b,
                       const float* __restrict__ out_b, const float* __restrict__ b_hh,
                       const float* __restrict__ regW, const float* __restrict__ reg_b,
                       float* __restrict__ bias_big){
  int i = blockIdx.x * 256 + threadIdx.x;
  if (i < 512){
    float s = emb_b[i];
    for (int k = 0; k < 256; k++) s += embW[i * 256 + k] * out_b[k];
    bias_big[i] = s;
  } else if (i < 2048){
    bias_big[i] = b_hh[i - 512];
  } else if (i < 2112){
    int o = i - 2048;
    float s = reg_b[o];
    for (int k = 0; k < 256; k++) s += regW[o * 256 + k] * out_b[k];
    bias_big[i] = s;
  }
}

// Generic C = A @ W^T (+bias). A: M x K (bf16 or f32), W: N x K bf16 row-major.
// mode 0: f32 out (ldc); 1: bf16 out; 2: relu + bf16 out; 3: f32 out with encoder (b,t) row remap
__global__ __launch_bounds__(256)
void k_gemm(const void* __restrict__ Aptr, int a_is_f32,
            const unsigned short* __restrict__ W,
            const float* __restrict__ bias,
            void* __restrict__ Cptr, int mode,
            int M, int N, int K, int ldc)
{
  const int lane = threadIdx.x & 63;
  const int wave = threadIdx.x >> 6;
  const int ln = lane & 15;
  const int kq = lane >> 4;
  const int m0 = blockIdx.y * 64 + wave * 16;
  const int n0 = blockIdx.x * 64;

  f32x4 acc[4] = {};
  const int arow = m0 + ln;
  const unsigned short* wp = W + (size_t)(n0 + ln) * K + kq * 8;
  const int nk = K >> 5;

  if (a_is_f32){
    const float* ap = (const float*)Aptr + (size_t)arow * K + kq * 8;
    for (int t = 0; t < nk; ++t){
      f32x4 u0 = *(const f32x4*)(ap);
      f32x4 u1 = *(const f32x4*)(ap + 4);
      bf16x8 af;
      af[0] = (short)f2b(u0[0]); af[1] = (short)f2b(u0[1]);
      af[2] = (short)f2b(u0[2]); af[3] = (short)f2b(u0[3]);
      af[4] = (short)f2b(u1[0]); af[5] = (short)f2b(u1[1]);
      af[6] = (short)f2b(u1[2]); af[7] = (short)f2b(u1[3]);
      #pragma unroll
      for (int j = 0; j < 4; j++){
        bf16x8 wf = *(const bf16x8*)(wp + (size_t)(16 * j) * K);
        acc[j] = __builtin_amdgcn_mfma_f32_16x16x32_bf16(af, wf, acc[j], 0, 0, 0);
      }
      ap += 32; wp += 32;
    }
  } else {
    const unsigned short* ap = (const unsigned short*)Aptr + (size_t)arow * K + kq * 8;
    for (int t = 0; t < nk; ++t){
      bf16x8 af = *(const bf16x8*)ap;
      #pragma unroll
      for (int j = 0; j < 4; j++){
        bf16x8 wf = *(const bf16x8*)(wp + (size_t)(16 * j) * K);
        acc[j] = __builtin_amdgcn_mfma_f32_16x16x32_bf16(af, wf, acc[j], 0, 0, 0);
      }
      ap += 32; wp += 32;
    }
  }

  #pragma unroll
  for (int j = 0; j < 4; j++){
    int col = n0 + 16 * j + ln;
    float bv = bias ? bias[col] : 0.0f;
    #pragma unroll
    for (int r = 0; r < 4; r++){
      int orow = m0 + kq * 4 + r;
      float v = acc[j][r] + bv;
      if (mode == 0){
        ((float*)Cptr)[(size_t)orow * ldc + col] = v;
      } else if (mode == 1){
        ((unsigned short*)Cptr)[(size_t)orow * ldc + col] = f2b(v);
      } else if (mode == 2){
        ((unsigned short*)Cptr)[(size_t)orow * ldc + col] = f2b(v > 0.f ? v : 0.f);
      } else {
        int bb = orow / T_ENC;
        int tt = orow - bb * T_ENC;
        ((float*)Cptr)[((size_t)bb * T_TOT + tt) * O_DIM + col] = v;
      }
    }
  }
}

// ---------------- persistent GRU loop (fence-free) ----------------

// grid barrier: all waves drain write-through stores (vmcnt), then counter add/poll.
// NO release/acquire fences -> no buffer_wbl2 / buffer_inv L2 tag walks.
static __device__ __forceinline__ void gbar(unsigned* cnt, unsigned tgt){
  asm volatile("s_waitcnt vmcnt(0)" ::: "memory");
  __syncthreads();
  if (threadIdx.x == 0){
    __hip_atomic_fetch_add(cnt, 1u, __ATOMIC_RELAXED, __HIP_MEMORY_SCOPE_AGENT);
    while (__hip_atomic_load(cnt, __ATOMIC_RELAXED, __HIP_MEMORY_SCOPE_AGENT) < tgt){
      __builtin_amdgcn_s_sleep(1);
    }
  }
  __syncthreads();
}

static __device__ __forceinline__ void emitA(unsigned short* __restrict__ e16,
                                             float* __restrict__ gh,
                                             float* __restrict__ out,
                                             int b, int colA, float v, int s){
  if (colA < 512){
    st_wt_u16(e16 + (size_t)b * H_DIM + colA, (unsigned)f2b(v > 0.f ? v : 0.f));
  } else if (colA < 2048){
    st_wt_f32(gh + (size_t)b * 1536 + (colA - 512), v);
  } else {
    out[((size_t)b * T_TOT + T_ENC + s) * O_DIM + (colA - 2048)] = v;   // normal store, never re-read
  }
}

// Phase A: 32-col supertile x half-M per block. af fragments preloaded (bypass), single vmcnt.
static __device__ __forceinline__ void phaseA2(
    const short* wA,
    const unsigned short* __restrict__ h16,
    unsigned short* __restrict__ e16,
    float* __restrict__ gh,
    float* __restrict__ out,
    int mbase, int ln, int kq, int colA0, float bvA0, float bvA1, int s)
{
  const unsigned short* r0 = h16 + (size_t)(mbase + ln) * H_DIM + kq * 8;
  const unsigned short* r1 = h16 + (size_t)(mbase + 16 + ln) * H_DIM + kq * 8;
  bf16x8 a0[16], a1[16];
  #pragma unroll
  for (int t = 0; t < 16; ++t){
    a0[t] = ld_bp(r0 + t * 32);
    a1[t] = ld_bp(r1 + t * 32);
  }
  wait_vm0();
  f32x4 acc00 = {}, acc01 = {}, acc10 = {}, acc11 = {};
  #pragma unroll
  for (int t = 0; t < 16; ++t){
    bf16x8 w0 = *(const bf16x8*)(wA + (t * 128 + ln * 4 + kq) * 8);
    bf16x8 w1 = *(const bf16x8*)(wA + (t * 128 + 64 + ln * 4 + kq) * 8);
    acc00 = __builtin_amdgcn_mfma_f32_16x16x32_bf16(a0[t], w0, acc00, 0, 0, 0);
    acc01 = __builtin_amdgcn_mfma_f32_16x16x32_bf16(a0[t], w1, acc01, 0, 0, 0);
    acc10 = __builtin_amdgcn_mfma_f32_16x16x32_bf16(a1[t], w0, acc10, 0, 0, 0);
    acc11 = __builtin_amdgcn_mfma_f32_16x16x32_bf16(a1[t], w1, acc11, 0, 0, 0);
  }
  #pragma unroll
  for (int r = 0; r < 4; ++r){
    int b0 = mbase + kq * 4 + r;
    int b1 = mbase + 16 + kq * 4 + r;
    emitA(e16, gh, out, b0, colA0,      acc00[r] + bvA0, s);
    emitA(e16, gh, out, b0, colA0 + 16, acc01[r] + bvA1, s);
    emitA(e16, gh, out, b1, colA0,      acc10[r] + bvA0, s);
    emitA(e16, gh, out, b1, colA0 + 16, acc11[r] + bvA1, s);
  }
}

// One block per CU. LDS: A-slice 32KB (32 cols of Wbig, blocks 0..131) + B-slice 48KB (48 gate-cols of w_ih).
// Phase A: 66 supertiles x 2 m-halves = 132 blocks. Phase B: 32 j-tiles x 8 m-slices = 256 blocks.
__global__ __launch_bounds__(512, 2)
void k_persist(const unsigned short* __restrict__ Wbig,
               const unsigned short* __restrict__ wih16,
               const float* __restrict__ bias_big,
               const float* __restrict__ b_ih,
               unsigned short* __restrict__ e16,
               float* __restrict__ gh,
               float* __restrict__ h,
               unsigned short* __restrict__ h16,
               float* __restrict__ out,
               unsigned* __restrict__ barcnt)
{
  __shared__ short lds_s[40960];          // 80 KiB: [0,16384) A, [16384,40960) B
  short* wA = lds_s;
  short* wB = lds_s + 16384;

  const int g    = blockIdx.x;
  const int tid  = threadIdx.x;
  const int wv   = tid >> 6;
  const int lane = tid & 63;
  const int ln   = lane & 15;
  const int kq   = lane >> 4;

  const int at2 = g >> 1;          // supertile (32 cols), valid for g < 132
  const int jt  = g & 31;
  const int mtB = g >> 5;

  // ---- stage weights into LDS (once), k-major 16B granules ----
  if (g < 132){
    // A: granule (kk, c in 0..31) -> phys (kk>>2)*128 + c*4 + (kk&3); per-t read is contiguous 2KB
    for (int q = tid; q < 2048; q += 512){
      int kk = q & 63, c = q >> 6;
      bf16x8 v = *(const bf16x8*)(Wbig + (size_t)(at2 * 32 + c) * H_DIM + kk * 8);
      int p = ((kk >> 2) << 7) + (c << 2) + (kk & 3);
      *(bf16x8*)(wA + p * 8) = v;
    }
  }
  // B: 48 cols = gate*16 + ln; granule (kk,c) -> phys (kk>>2)*192 + c*4 + (kk&3)
  for (int q = tid; q < 3072; q += 512){
    int kk = q & 63, c = q >> 6;
    int row = ((c >> 4) << 9) + jt * 16 + (c & 15);
    bf16x8 v = *(const bf16x8*)(wih16 + (size_t)row * H_DIM + kk * 8);
    int p = (kk >> 2) * 192 + (c << 2) + (kk & 3);
    *(bf16x8*)(wB + p * 8) = v;
  }
  __syncthreads();

  // hoisted per-thread constants
  const int jcol = jt * 16 + ln;
  const float bR = b_ih[jcol], bZ = b_ih[512 + jcol], bN = b_ih[1024 + jcol];
  const int colA0 = at2 * 32 + ln;                        // valid when g < 132
  const float bvA0 = bias_big[(g < 132) ? colA0 : 0];
  const float bvA1 = bias_big[(g < 132) ? (colA0 + 16) : 0];

  unsigned gen = 0;
  for (int s = 0; s < PRED; ++s){
    // ---- phase B: gi = e16 @ w_ih^T slice, GRU gating -> h, h16 ----
    if (wv < 4){
      const int m0 = mtB * 64 + wv * 16;
      const unsigned short* ap = e16 + (size_t)(m0 + ln) * H_DIM + kq * 8;
      bf16x8 af[16];
      #pragma unroll
      for (int t = 0; t < 16; ++t) af[t] = ld_bp(ap + t * 32);
      float gR[4], gZ[4], gN[4];
      #pragma unroll
      for (int r = 0; r < 4; ++r){
        const float* ghrow = gh + (size_t)(m0 + kq * 4 + r) * 1536;
        gR[r] = ld_bp_f32(ghrow + jcol);
        gZ[r] = ld_bp_f32(ghrow + 512 + jcol);
        gN[r] = ld_bp_f32(ghrow + 1024 + jcol);
      }
      wait_vm0();
      f32x4 aR = {}, aZ = {}, aN = {};
      const short* lb = wB + (ln * 4 + kq) * 8;
      #pragma unroll
      for (int t = 0; t < 16; ++t){
        aR = __builtin_amdgcn_mfma_f32_16x16x32_bf16(af[t], *(const bf16x8*)(lb + (t * 192      ) * 8), aR, 0, 0, 0);
        aZ = __builtin_amdgcn_mfma_f32_16x16x32_bf16(af[t], *(const bf16x8*)(lb + (t * 192 +  64) * 8), aZ, 0, 0, 0);
        aN = __builtin_amdgcn_mfma_f32_16x16x32_bf16(af[t], *(const bf16x8*)(lb + (t * 192 + 128) * 8), aN, 0, 0, 0);
      }
      #pragma unroll
      for (int r = 0; r < 4; ++r){
        int b = m0 + kq * 4 + r;
        float rg = sigmoidf_(aR[r] + bR + gR[r]);
        float z  = sigmoidf_(aZ[r] + bZ + gZ[r]);
        float nn = tanhf_(aN[r] + bN + rg * gN[r]);
        float hv = (1.f - z) * nn + z * h[(size_t)b * H_DIM + jcol];   // h is block-private: normal cache OK
        h[(size_t)b * H_DIM + jcol] = hv;
        st_wt_u16(h16 + (size_t)b * H_DIM + jcol, (unsigned)f2b(hv));
      }
    }
    gen++; gbar(barcnt, gen * NBLK);

    // ---- phase A: T = h16 @ Wbig^T supertile -> e16 / gh / out ----
    if (g < 132 && (s < PRED - 1 || at2 >= 64)){
      phaseA2(wA, h16, e16, gh, out, (g & 1) * 256 + wv * 32, ln, kq, colA0, bvA0, bvA1, s);
    }
    if (s < PRED - 1){
      gen++; gbar(barcnt, gen * NBLK);
    }
  }
}

extern "C" void kernel_launch(void* const* d_in, const int* in_sizes, int n_in,
                              void* d_out, int out_size, void* d_ws, size_t ws_size,
                              hipStream_t stream)
{
  const float* enc   = (const float*)d_in[0];
  const float* ehid  = (const float*)d_in[1];
  const float* embW  = (const float*)d_in[2];
  const float* emb_b = (const float*)d_in[3];
  const float* w_ih  = (const float*)d_in[4];
  const float* w_hh  = (const float*)d_in[5];
  const float* b_ih  = (const float*)d_in[6];
  const float* b_hh  = (const float*)d_in[7];
  const float* out_W = (const float*)d_in[8];
  const float* out_b = (const float*)d_in[9];
  const float* reg_W = (const float*)d_in[10];
  const float* reg_b = (const float*)d_in[11];
  float* out = (float*)d_out;

  char* ws = (char*)d_ws;
  size_t off = 0;
  auto alloc = [&](size_t bytes)->char*{
    char* p = ws + off; off += (bytes + 255) & ~(size_t)255; return p;
  };
  unsigned short* Wbig    = (unsigned short*)alloc((size_t)2112 * 512 * 2);
  unsigned short* wih16   = (unsigned short*)alloc((size_t)1536 * 512 * 2);
  unsigned short* embW16  = (unsigned short*)alloc((size_t)512 * 256 * 2);
  unsigned short* regW16  = (unsigned short*)alloc((size_t)64 * 256 * 2);
  unsigned short* outWT16 = (unsigned short*)alloc((size_t)512 * 256 * 2);
  float*          bias_big= (float*)alloc((size_t)2112 * 4);
  unsigned short* e16     = (unsigned short*)alloc((size_t)512 * 512 * 2);
  float*          gh      = (float*)alloc((size_t)512 * 1536 * 4);
  float*          h       = (float*)alloc((size_t)512 * 512 * 4);
  unsigned short* h16     = (unsigned short*)alloc((size_t)512 * 512 * 2);
  unsigned short* x016    = (unsigned short*)alloc((size_t)512 * 256 * 2);
  unsigned*       barcnt  = (unsigned*)alloc(256);

  hipMemsetAsync(barcnt, 0, 64, stream);

  // ---- precompute (runs every call; ws is re-poisoned) ----
  k_cast<<<(1536 * 512) / 256, 256, 0, stream>>>(w_ih, wih16, 1536 * 512);
  k_cast<<<(1536 * 512) / 256, 256, 0, stream>>>(w_hh, Wbig + (size_t)512 * 512, 1536 * 512);
  k_cast<<<(512 * 256) / 256, 256, 0, stream>>>(embW, embW16, 512 * 256);
  k_cast<<<(64 * 256) / 256, 256, 0, stream>>>(reg_W, regW16, 64 * 256);
  k_transpose_cast<<<512, 256, 0, stream>>>(out_W, outWT16);
  k_bias<<<9, 256, 0, stream>>>(embW, emb_b, out_b, b_hh, reg_W, reg_b, bias_big);
  k_init_h<<<(512 * 512) / 256, 256, 0, stream>>>(ehid, h, h16);
  k_x0<<<(512 * 256) / 256, 256, 0, stream>>>(enc, x016);

  // W_comb = emb_W @ out_W  -> Wbig rows [0,512)
  k_gemm<<<dim3(8, 8), 256, 0, stream>>>(embW, 1, outWT16, nullptr, Wbig, 1, 512, 512, 256, 512);
  // W_or = reg_W @ out_W  -> Wbig rows [2048,2112)
  k_gemm<<<dim3(8, 1), 256, 0, stream>>>(reg_W, 1, outWT16, nullptr, Wbig + (size_t)2048 * 512, 1, 64, 512, 256, 512);
  // e0 = relu(x0 @ emb_W^T + emb_b)
  k_gemm<<<dim3(8, 8), 256, 0, stream>>>(x016, 0, embW16, emb_b, e16, 2, 512, 512, 256, 512);
  // gh0 = h0 @ w_hh^T + b_hh
  k_gemm<<<dim3(24, 8), 256, 0, stream>>>(h16, 0, Wbig + (size_t)512 * 512, b_hh, gh, 0, 512, 1536, 512, 1536);
  // encoder projection: out[:, 0:140, :] = enc @ reg_W^T + reg_b
  k_gemm<<<dim3(1, 1120), 256, 0, stream>>>(enc, 1, regW16, reg_b, out, 3, 71680, 64, 256, 0);

  // ---- 140 GRU steps in ONE persistent kernel (fence-free barriers) ----
  k_persist<<<dim3(NBLK), dim3(512), 0, stream>>>(Wbig, wih16, bias_big, b_ih,
                                                  e16, gh, h, h16, out, barcnt);
}

// Round 3
// 5212.525 us; speedup vs baseline: 1.5341x; 1.0492x over previous
//
#include <hip/hip_runtime.h>

#define B_SZ 512
#define T_ENC 140
#define E_DIM 256
#define H_DIM 512
#define O_DIM 64
#define PRED 140
#define T_TOT 280
#define NBLK 256

typedef short bf16x8 __attribute__((ext_vector_type(8)));
typedef float f32x4 __attribute__((ext_vector_type(4)));
typedef unsigned u32x4 __attribute__((ext_vector_type(4)));

static __device__ __forceinline__ unsigned short f2b(float x){
  union { float f; unsigned u; } v; v.f = x;
  unsigned r = v.u + 0x7fffu + ((v.u >> 16) & 1u);
  return (unsigned short)(r >> 16);
}
static __device__ __forceinline__ float sigmoidf_(float x){
  return 1.0f / (1.0f + __expf(-x));
}
static __device__ __forceinline__ float tanhf_(float x){
  float e2 = __expf(-2.0f * fabsf(x));
  float t = (1.0f - e2) / (1.0f + e2);
  return x < 0.0f ? -t : t;
}

// ---- device-coherent (L3) access: bypass L1/L2 so no fence/invalidate is ever needed ----
static __device__ __forceinline__ void st_wt_u16(unsigned short* p, unsigned v){
  asm volatile("global_store_short %0, %1, off sc0 sc1" :: "v"(p), "v"(v) : "memory");
}
static __device__ __forceinline__ void st_wt_f32(float* p, float v){
  asm volatile("global_store_dword %0, %1, off sc0 sc1" :: "v"(p), "v"(v) : "memory");
}
static __device__ __forceinline__ void st_wt_u32(unsigned* p, unsigned v){
  asm volatile("global_store_dword %0, %1, off sc0 sc1" :: "v"(p), "v"(v) : "memory");
}
static __device__ __forceinline__ bf16x8 ld_bp(const unsigned short* p){
  f32x4 r;
  asm volatile("global_load_dwordx4 %0, %1, off sc0 sc1" : "=v"(r) : "v"(p));
  union { f32x4 f; bf16x8 b; } u; u.f = r; return u.b;
}
static __device__ __forceinline__ float ld_bp_f32(const float* p){
  float r;
  asm volatile("global_load_dword %0, %1, off sc0 sc1" : "=v"(r) : "v"(p));
  return r;
}
static __device__ __forceinline__ void wait_vm0(){
  asm volatile("s_waitcnt vmcnt(0)" ::: "memory");
  __builtin_amdgcn_sched_barrier(0);
}
// poll loads: embed the waitcnt (compiler doesn't track asm vmcnt)
static __device__ __forceinline__ u32x4 ld_poll4(const unsigned* p){
  u32x4 r;
  asm volatile("global_load_dwordx4 %0, %1, off sc0 sc1\n\ts_waitcnt vmcnt(0)"
               : "=v"(r) : "v"(p) : "memory");
  return r;
}
static __device__ __forceinline__ unsigned ld_poll1(const unsigned* p){
  unsigned r;
  asm volatile("global_load_dword %0, %1, off sc0 sc1\n\ts_waitcnt vmcnt(0)"
               : "=v"(r) : "v"(p) : "memory");
  return r;
}

__global__ void k_cast(const float* __restrict__ src, unsigned short* __restrict__ dst, int n){
  int i = blockIdx.x * 256 + threadIdx.x;
  if (i < n) dst[i] = f2b(src[i]);
}

// out_W (E x H) -> outWT16 (H x E) bf16
__global__ void k_transpose_cast(const float* __restrict__ src, unsigned short* __restrict__ dst){
  int i = blockIdx.x * 256 + threadIdx.x;   // over H*E = 131072
  int j = i >> 8;
  int k = i & 255;
  dst[i] = f2b(src[k * H_DIM + j]);
}

__global__ void k_init_h(const float* __restrict__ eh, float* __restrict__ h, unsigned short* __restrict__ h16){
  int i = blockIdx.x * 256 + threadIdx.x;   // B*H
  float v = eh[i];
  h[i] = v; h16[i] = f2b(v);
}

__global__ void k_x0(const float* __restrict__ enc, unsigned short* __restrict__ x016){
  int i = blockIdx.x * 256 + threadIdx.x;   // B*E
  int b = i >> 8; int k = i & 255;
  x016[i] = f2b(enc[((size_t)b * T_ENC + (T_ENC - 1)) * E_DIM + k]);
}

// bias_big = [emb_b + emb_W@out_b (512) | b_hh (1536) | reg_b + reg_W@out_b (64)]
__global__ void k_bias(const float* __restrict__ embW, const float* __restrict__ emb_b,
                       const float* __restrict__ out_b, const float* __restrict__ b_hh,
                       const float* __restrict__ regW, const float* __restrict__ reg_b,
                       float* __restrict__ bias_big){
  int i = blockIdx.x * 256 + threadIdx.x;
  if (i < 512){
    float s = emb_b[i];
    for (int k = 0; k < 256; k++) s += embW[i * 256 + k] * out_b[k];
    bias_big[i] = s;
  } else if (i < 2048){
    bias_big[i] = b_hh[i - 512];
  } else if (i < 2112){
    int o = i - 2048;
    float s = reg_b[o];
    for (int k = 0; k < 256; k++) s += regW[o * 256 + k] * out_b[k];
    bias_big[i] = s;
  }
}

// Generic C = A @ W^T (+bias). A: M x K (bf16 or f32), W: N x K bf16 row-major.
// mode 0: f32 out (ldc); 1: bf16 out; 2: relu + bf16 out; 3: f32 out with encoder (b,t) row remap
__global__ __launch_bounds__(256)
void k_gemm(const void* __restrict__ Aptr, int a_is_f32,
            const unsigned short* __restrict__ W,
            const float* __restrict__ bias,
            void* __restrict__ Cptr, int mode,
            int M, int N, int K, int ldc)
{
  const int lane = threadIdx.x & 63;
  const int wave = threadIdx.x >> 6;
  const int ln = lane & 15;
  const int kq = lane >> 4;
  const int m0 = blockIdx.y * 64 + wave * 16;
  const int n0 = blockIdx.x * 64;

  f32x4 acc[4] = {};
  const int arow = m0 + ln;
  const unsigned short* wp = W + (size_t)(n0 + ln) * K + kq * 8;
  const int nk = K >> 5;

  if (a_is_f32){
    const float* ap = (const float*)Aptr + (size_t)arow * K + kq * 8;
    for (int t = 0; t < nk; ++t){
      f32x4 u0 = *(const f32x4*)(ap);
      f32x4 u1 = *(const f32x4*)(ap + 4);
      bf16x8 af;
      af[0] = (short)f2b(u0[0]); af[1] = (short)f2b(u0[1]);
      af[2] = (short)f2b(u0[2]); af[3] = (short)f2b(u0[3]);
      af[4] = (short)f2b(u1[0]); af[5] = (short)f2b(u1[1]);
      af[6] = (short)f2b(u1[2]); af[7] = (short)f2b(u1[3]);
      #pragma unroll
      for (int j = 0; j < 4; j++){
        bf16x8 wf = *(const bf16x8*)(wp + (size_t)(16 * j) * K);
        acc[j] = __builtin_amdgcn_mfma_f32_16x16x32_bf16(af, wf, acc[j], 0, 0, 0);
      }
      ap += 32; wp += 32;
    }
  } else {
    const unsigned short* ap = (const unsigned short*)Aptr + (size_t)arow * K + kq * 8;
    for (int t = 0; t < nk; ++t){
      bf16x8 af = *(const bf16x8*)ap;
      #pragma unroll
      for (int j = 0; j < 4; j++){
        bf16x8 wf = *(const bf16x8*)(wp + (size_t)(16 * j) * K);
        acc[j] = __builtin_amdgcn_mfma_f32_16x16x32_bf16(af, wf, acc[j], 0, 0, 0);
      }
      ap += 32; wp += 32;
    }
  }

  #pragma unroll
  for (int j = 0; j < 4; j++){
    int col = n0 + 16 * j + ln;
    float bv = bias ? bias[col] : 0.0f;
    #pragma unroll
    for (int r = 0; r < 4; r++){
      int orow = m0 + kq * 4 + r;
      float v = acc[j][r] + bv;
      if (mode == 0){
        ((float*)Cptr)[(size_t)orow * ldc + col] = v;
      } else if (mode == 1){
        ((unsigned short*)Cptr)[(size_t)orow * ldc + col] = f2b(v);
      } else if (mode == 2){
        ((unsigned short*)Cptr)[(size_t)orow * ldc + col] = f2b(v > 0.f ? v : 0.f);
      } else {
        int bb = orow / T_ENC;
        int tt = orow - bb * T_ENC;
        ((float*)Cptr)[((size_t)bb * T_TOT + tt) * O_DIM + col] = v;
      }
    }
  }
}

// ---------------- persistent GRU loop (fence-free, contention-free barrier) ----------------

// Hierarchical barrier:
//  arrival: block g write-through-stores `gen` into its OWN slot (no RMW, no shared-line polling)
//  block 0 wave 0 polls all 256 slots with one dwordx4 per lane, then writes 8 replicated
//  release-flag lines (256B apart); block g polls only flag line (g&7)  -> <=32 pollers/line.
static __device__ __forceinline__ void gbar(unsigned* slots, unsigned* flags, int g, unsigned gen){
  asm volatile("s_waitcnt vmcnt(0)" ::: "memory");   // drain this block's write-through data stores
  __syncthreads();
  if (g == 0){
    if (threadIdx.x < 64){
      if (threadIdx.x == 0) st_wt_u32(slots, gen);
      const unsigned* myp = slots + threadIdx.x * 4;
      for (;;){
        u32x4 v = ld_poll4(myp);
        int ok = (v[0] >= gen) & (v[1] >= gen) & (v[2] >= gen) & (v[3] >= gen);
        if (__all(ok)) break;
        __builtin_amdgcn_s_sleep(2);
      }
      if (threadIdx.x < 8) st_wt_u32(flags + threadIdx.x * 64, gen);
    }
  } else {
    if (threadIdx.x == 0){
      st_wt_u32(slots + g, gen);
      while (ld_poll1(flags + (g & 7) * 64) < gen){
        __builtin_amdgcn_s_sleep(2);
      }
    }
  }
  __syncthreads();
}

static __device__ __forceinline__ void emitA(unsigned short* __restrict__ e16,
                                             float* __restrict__ gh,
                                             float* __restrict__ out,
                                             int b, int colA, float v, int s){
  if (colA < 512){
    st_wt_u16(e16 + (size_t)b * H_DIM + colA, (unsigned)f2b(v > 0.f ? v : 0.f));
  } else if (colA < 2048){
    st_wt_f32(gh + (size_t)b * 1536 + (colA - 512), v);
  } else {
    out[((size_t)b * T_TOT + T_ENC + s) * O_DIM + (colA - 2048)] = v;   // normal store, never re-read
  }
}

// One block per CU. LDS: A-slice 64KB (64 cols of Wbig, blocks 0..65) + B-slice 48KB (48 gate-cols of w_ih).
// Phase A: 33 supertiles (64 cols) x 2 m-halves = 66 blocks. Phase B: 32 j-tiles x 8 m-slices = 256 blocks.
__global__ __launch_bounds__(512, 2)
void k_persist(const unsigned short* __restrict__ Wbig,
               const unsigned short* __restrict__ wih16,
               const float* __restrict__ bias_big,
               const float* __restrict__ b_ih,
               unsigned short* __restrict__ e16,
               float* __restrict__ gh,
               float* __restrict__ h,
               unsigned short* __restrict__ h16,
               float* __restrict__ out,
               unsigned* __restrict__ slots,
               unsigned* __restrict__ flags)
{
  __shared__ short lds_s[57344];          // 112 KiB: [0,32768) A (64KB), [32768,57344) B (48KB)
  short* wA = lds_s;
  short* wB = lds_s + 32768;

  const int g    = blockIdx.x;
  const int tid  = threadIdx.x;
  const int wv   = tid >> 6;
  const int lane = tid & 63;
  const int ln   = lane & 15;
  const int kq   = lane >> 4;

  const int at2 = g >> 1;          // supertile (64 cols), valid for g < 66
  const int jt  = g & 31;
  const int mtB = g >> 5;

  // ---- stage weights into LDS (once), k-major 16B granules ----
  if (g < 66){
    // A: granule (kk, c in 0..63) -> phys (kk>>2)*256 + c*4 + (kk&3); per-(t,jn) read is contiguous 1KB
    for (int q = tid; q < 4096; q += 512){
      int kk = q & 63, c = q >> 6;
      bf16x8 v = *(const bf16x8*)(Wbig + (size_t)(at2 * 64 + c) * H_DIM + kk * 8);
      int p = ((kk >> 2) << 8) + (c << 2) + (kk & 3);
      *(bf16x8*)(wA + p * 8) = v;
    }
  }
  // B: 48 cols = gate*16 + ln; granule (kk,c) -> phys (kk>>2)*192 + c*4 + (kk&3)
  for (int q = tid; q < 3072; q += 512){
    int kk = q & 63, c = q >> 6;
    int row = ((c >> 4) << 9) + jt * 16 + (c & 15);
    bf16x8 v = *(const bf16x8*)(wih16 + (size_t)row * H_DIM + kk * 8);
    int p = (kk >> 2) * 192 + (c << 2) + (kk & 3);
    *(bf16x8*)(wB + p * 8) = v;
  }
  __syncthreads();

  // hoisted per-thread constants
  const int jcol = jt * 16 + ln;
  const float bR = b_ih[jcol], bZ = b_ih[512 + jcol], bN = b_ih[1024 + jcol];
  float bvA[4];
  #pragma unroll
  for (int jn = 0; jn < 4; ++jn)
    bvA[jn] = bias_big[(g < 66) ? (at2 * 64 + jn * 16 + ln) : 0];

  unsigned gen = 0;
  for (int s = 0; s < PRED; ++s){
    // ---- phase B: gi = e16 @ w_ih^T slice, GRU gating -> h, h16 ----
    if (wv < 4){
      const int m0 = mtB * 64 + wv * 16;
      const unsigned short* ap = e16 + (size_t)(m0 + ln) * H_DIM + kq * 8;
      bf16x8 af[16];
      #pragma unroll
      for (int t = 0; t < 16; ++t) af[t] = ld_bp(ap + t * 32);
      float gR[4], gZ[4], gN[4];
      #pragma unroll
      for (int r = 0; r < 4; ++r){
        const float* ghrow = gh + (size_t)(m0 + kq * 4 + r) * 1536;
        gR[r] = ld_bp_f32(ghrow + jcol);
        gZ[r] = ld_bp_f32(ghrow + 512 + jcol);
        gN[r] = ld_bp_f32(ghrow + 1024 + jcol);
      }
      wait_vm0();
      f32x4 aR = {}, aZ = {}, aN = {};
      const short* lb = wB + (ln * 4 + kq) * 8;
      #pragma unroll
      for (int t = 0; t < 16; ++t){
        aR = __builtin_amdgcn_mfma_f32_16x16x32_bf16(af[t], *(const bf16x8*)(lb + (t * 192      ) * 8), aR, 0, 0, 0);
        aZ = __builtin_amdgcn_mfma_f32_16x16x32_bf16(af[t], *(const bf16x8*)(lb + (t * 192 +  64) * 8), aZ, 0, 0, 0);
        aN = __builtin_amdgcn_mfma_f32_16x16x32_bf16(af[t], *(const bf16x8*)(lb + (t * 192 + 128) * 8), aN, 0, 0, 0);
      }
      #pragma unroll
      for (int r = 0; r < 4; ++r){
        int b = m0 + kq * 4 + r;
        float rg = sigmoidf_(aR[r] + bR + gR[r]);
        float z  = sigmoidf_(aZ[r] + bZ + gZ[r]);
        float nn = tanhf_(aN[r] + bN + rg * gN[r]);
        float hv = (1.f - z) * nn + z * h[(size_t)b * H_DIM + jcol];   // h is block-private: normal cache OK
        h[(size_t)b * H_DIM + jcol] = hv;
        st_wt_u16(h16 + (size_t)b * H_DIM + jcol, (unsigned)f2b(hv));
      }
    }
    gen++; gbar(slots, flags, g, gen);

    // ---- phase A: T = h16 @ Wbig^T supertile (64 cols x half-M) -> e16 / gh / out ----
    if (g < 66 && (s < PRED - 1 || at2 == 32)){
      const int mhalf = (g & 1) * 256;
      #pragma unroll
      for (int f = 0; f < 2; ++f){
        const int mbase = mhalf + wv * 32 + f * 16;
        const unsigned short* rp = h16 + (size_t)(mbase + ln) * H_DIM + kq * 8;
        bf16x8 a[16];
        #pragma unroll
        for (int t = 0; t < 16; ++t) a[t] = ld_bp(rp + t * 32);
        wait_vm0();
        f32x4 acc[4] = {};
        #pragma unroll
        for (int t = 0; t < 16; ++t){
          #pragma unroll
          for (int jn = 0; jn < 4; ++jn){
            bf16x8 w = *(const bf16x8*)(wA + (t * 256 + (jn * 16 + ln) * 4 + kq) * 8);
            acc[jn] = __builtin_amdgcn_mfma_f32_16x16x32_bf16(a[t], w, acc[jn], 0, 0, 0);
          }
        }
        #pragma unroll
        for (int jn = 0; jn < 4; ++jn){
          int col = at2 * 64 + jn * 16 + ln;
          #pragma unroll
          for (int r = 0; r < 4; ++r){
            emitA(e16, gh, out, mbase + kq * 4 + r, col, acc[jn][r] + bvA[jn], s);
          }
        }
      }
    }
    if (s < PRED - 1){
      gen++; gbar(slots, flags, g, gen);
    }
  }
}

extern "C" void kernel_launch(void* const* d_in, const int* in_sizes, int n_in,
                              void* d_out, int out_size, void* d_ws, size_t ws_size,
                              hipStream_t stream)
{
  const float* enc   = (const float*)d_in[0];
  const float* ehid  = (const float*)d_in[1];
  const float* embW  = (const float*)d_in[2];
  const float* emb_b = (const float*)d_in[3];
  const float* w_ih  = (const float*)d_in[4];
  const float* w_hh  = (const float*)d_in[5];
  const float* b_ih  = (const float*)d_in[6];
  const float* b_hh  = (const float*)d_in[7];
  const float* out_W = (const float*)d_in[8];
  const float* out_b = (const float*)d_in[9];
  const float* reg_W = (const float*)d_in[10];
  const float* reg_b = (const float*)d_in[11];
  float* out = (float*)d_out;

  char* ws = (char*)d_ws;
  size_t off = 0;
  auto alloc = [&](size_t bytes)->char*{
    char* p = ws + off; off += (bytes + 255) & ~(size_t)255; return p;
  };
  unsigned short* Wbig    = (unsigned short*)alloc((size_t)2112 * 512 * 2);
  unsigned short* wih16   = (unsigned short*)alloc((size_t)1536 * 512 * 2);
  unsigned short* embW16  = (unsigned short*)alloc((size_t)512 * 256 * 2);
  unsigned short* regW16  = (unsigned short*)alloc((size_t)64 * 256 * 2);
  unsigned short* outWT16 = (unsigned short*)alloc((size_t)512 * 256 * 2);
  float*          bias_big= (float*)alloc((size_t)2112 * 4);
  unsigned short* e16     = (unsigned short*)alloc((size_t)512 * 512 * 2);
  float*          gh      = (float*)alloc((size_t)512 * 1536 * 4);
  float*          h       = (float*)alloc((size_t)512 * 512 * 4);
  unsigned short* h16     = (unsigned short*)alloc((size_t)512 * 512 * 2);
  unsigned short* x016    = (unsigned short*)alloc((size_t)512 * 256 * 2);
  unsigned*       slots   = (unsigned*)alloc(4096);   // 256 arrival slots + 8 release-flag lines
  unsigned*       flags   = slots + 256;              // flags at +1KB, 8 copies 256B apart

  hipMemsetAsync(slots, 0, 4096, stream);

  // ---- precompute (runs every call; ws is re-poisoned) ----
  k_cast<<<(1536 * 512) / 256, 256, 0, stream>>>(w_ih, wih16, 1536 * 512);
  k_cast<<<(1536 * 512) / 256, 256, 0, stream>>>(w_hh, Wbig + (size_t)512 * 512, 1536 * 512);
  k_cast<<<(512 * 256) / 256, 256, 0, stream>>>(embW, embW16, 512 * 256);
  k_cast<<<(64 * 256) / 256, 256, 0, stream>>>(reg_W, regW16, 64 * 256);
  k_transpose_cast<<<512, 256, 0, stream>>>(out_W, outWT16);
  k_bias<<<9, 256, 0, stream>>>(embW, emb_b, out_b, b_hh, reg_W, reg_b, bias_big);
  k_init_h<<<(512 * 512) / 256, 256, 0, stream>>>(ehid, h, h16);
  k_x0<<<(512 * 256) / 256, 256, 0, stream>>>(enc, x016);

  // W_comb = emb_W @ out_W  -> Wbig rows [0,512)
  k_gemm<<<dim3(8, 8), 256, 0, stream>>>(embW, 1, outWT16, nullptr, Wbig, 1, 512, 512, 256, 512);
  // W_or = reg_W @ out_W  -> Wbig rows [2048,2112)
  k_gemm<<<dim3(8, 1), 256, 0, stream>>>(reg_W, 1, outWT16, nullptr, Wbig + (size_t)2048 * 512, 1, 64, 512, 256, 512);
  // e0 = relu(x0 @ emb_W^T + emb_b)
  k_gemm<<<dim3(8, 8), 256, 0, stream>>>(x016, 0, embW16, emb_b, e16, 2, 512, 512, 256, 512);
  // gh0 = h0 @ w_hh^T + b_hh
  k_gemm<<<dim3(24, 8), 256, 0, stream>>>(h16, 0, Wbig + (size_t)512 * 512, b_hh, gh, 0, 512, 1536, 512, 1536);
  // encoder projection: out[:, 0:140, :] = enc @ reg_W^T + reg_b
  k_gemm<<<dim3(1, 1120), 256, 0, stream>>>(enc, 1, regW16, reg_b, out, 3, 71680, 64, 256, 0);

  // ---- 140 GRU steps in ONE persistent kernel (hierarchical fence-free barriers) ----
  k_persist<<<dim3(NBLK), dim3(512), 0, stream>>>(Wbig, wih16, bias_big, b_ih,
                                                  e16, gh, h, h16, out, slots, flags);
}